// Round 1
// 393.180 us; speedup vs baseline: 1.0169x; 1.0169x over previous
//
#include <hip/hip_runtime.h>
#include <math.h>

#define F_CH 12
#define C_DIM 200
#define HW 225
#define PERB (C_DIM*HW)      /* 45000 */
#define PERB4 (PERB/4)       /* 11250 */
#define LN_EPS 1e-5f

/* ws layout (floats) */
#define WS_WT   0        /* 7200: wT[c][36] = {w11[:,c], w21[:,c], w31[:,c]} */
#define WS_DP   7200     /* 200:  D'[c] = d[c] - mean(d) */
#define WS_DG   7400     /* 200:  Dg[c] = D'[c]*ln_g[c] */
#define WS_VARD 7600     /* 1:    mean(D'^2) */
#define WS_PAR  7616     /* per-batch params: P[225], R[225], Ag[200], stride 656 */
#define PSTRIDE 656
#define WS_NEEDED_BYTES ((size_t)(WS_PAR + PSTRIDE*1024) * 4)

#define CSPL 4           /* c-segments per batch in k_gate */
#define CPB  (C_DIM/CSPL)/* 50 */

__global__ __launch_bounds__(256) void k_prep(
    const float* __restrict__ w11, const float* __restrict__ w21,
    const float* __restrict__ w31, const float* __restrict__ b41,
    const float* __restrict__ w42, const float* __restrict__ b42,
    const float* __restrict__ ln_g,
    float* __restrict__ wT, float* __restrict__ Dp, float* __restrict__ Dg,
    float* __restrict__ varD)
{
    const int tid = threadIdx.x;
    for (int i = tid; i < 36*C_DIM; i += 256) {
        int c = i / 36, g = i - 36*c;
        float v;
        if (g < 12)      v = w11[g*C_DIM + c];
        else if (g < 24) v = w21[(g-12)*C_DIM + c];
        else             v = w31[(g-24)*C_DIM + c];
        wT[i] = v;
    }
    __shared__ float red[12];
    __shared__ float DmSh;
    float d = 0.f;
    if (tid < C_DIM) {
        float s = b42[tid];
#pragma unroll
        for (int j = 0; j < 6; ++j) s = fmaf(w42[tid*6+j], b41[j], s);
        d = s;
    }
    float s0 = d;
    for (int o = 32; o > 0; o >>= 1) s0 += __shfl_down(s0, o, 64);
    if ((tid & 63) == 0) red[tid >> 6] = s0;
    __syncthreads();
    if (tid == 0) DmSh = (red[0]+red[1]+red[2]+red[3]) * (1.f/C_DIM);
    __syncthreads();
    float dp = (tid < C_DIM) ? (d - DmSh) : 0.f;
    if (tid < C_DIM) { Dp[tid] = dp; Dg[tid] = dp * ln_g[tid]; }
    float s1 = dp*dp;
    for (int o = 32; o > 0; o >>= 1) s1 += __shfl_down(s1, o, 64);
    if ((tid & 63) == 0) red[4 + (tid >> 6)] = s1;
    __syncthreads();
    if (tid == 0) varD[0] = (red[4]+red[5]+red[6]+red[7]) * (1.f/C_DIM);
}

/* ---------- split path: conv + reductions -> per-batch gate params ---------- */
__global__ __launch_bounds__(256) void k_conv(
    const float* __restrict__ X,
    const float* __restrict__ wT,
    const float* __restrict__ b11, const float* __restrict__ b21,
    const float* __restrict__ b31,
    const float* __restrict__ w41,
    const float* __restrict__ w42,
    const float* __restrict__ Dp, const float* __restrict__ varDp,
    const float* __restrict__ ln_g,
    float* __restrict__ par)
{
    const int b   = blockIdx.x;
    const int tid = threadIdx.x;

    __shared__ float vmb[F_CH];
    __shared__ float vsS[F_CH];
    __shared__ float t1S[6];
    __shared__ float red[12];
    __shared__ float AmSh, varASh, covSh;

    const float varD = varDp[0];

    float accK[F_CH], accQ[F_CH], accV[F_CH];
#pragma unroll
    for (int f = 0; f < F_CH; ++f) { accK[f] = b11[f]; accQ[f] = b21[f]; accV[f] = b31[f]; }

    /* All 256 threads run the loop (wave-uniform scalar weight loads);
       lanes >= 225 duplicate pixel 224 and are masked from stores/reductions. */
    const int n = (tid < HW) ? tid : (HW-1);
    const float* xcol = X + (size_t)b*PERB + n;

    /* unroll x4 with explicit next-group prefetch: 4 loads in flight per wave */
    float x0 = xcol[0], x1 = xcol[HW], x2 = xcol[2*HW], x3 = xcol[3*HW];
    for (int c = 0; c < C_DIM; c += 4) {
        float y0 = 0.f, y1 = 0.f, y2 = 0.f, y3 = 0.f;
        if (c + 4 < C_DIM) {
            const float* xn4 = xcol + (size_t)(c+4)*HW;
            y0 = xn4[0]; y1 = xn4[HW]; y2 = xn4[2*HW]; y3 = xn4[3*HW];
        }
        const float* wr = wT + c*36;
#pragma unroll
        for (int f = 0; f < F_CH; ++f) {
            accK[f] = fmaf(x0, wr[f],       accK[f]);
            accQ[f] = fmaf(x0, wr[12+f],    accQ[f]);
            accV[f] = fmaf(x0, wr[24+f],    accV[f]);
            accK[f] = fmaf(x1, wr[36+f],    accK[f]);
            accQ[f] = fmaf(x1, wr[48+f],    accQ[f]);
            accV[f] = fmaf(x1, wr[60+f],    accV[f]);
            accK[f] = fmaf(x2, wr[72+f],    accK[f]);
            accQ[f] = fmaf(x2, wr[84+f],    accQ[f]);
            accV[f] = fmaf(x2, wr[96+f],    accV[f]);
            accK[f] = fmaf(x3, wr[108+f],   accK[f]);
            accQ[f] = fmaf(x3, wr[120+f],   accQ[f]);
            accV[f] = fmaf(x3, wr[132+f],   accV[f]);
        }
        x0 = y0; x1 = y1; x2 = y2; x3 = y3;
    }

    /* kq stays in a register (no kqsS round-trip needed anymore) */
    float kq = 0.f;
#pragma unroll
    for (int f = 0; f < F_CH; ++f) kq = fmaf(accK[f], accQ[f], kq);

    if (tid < F_CH) vmb[tid] = 0.f;
    __syncthreads();

    /* vm bucketing: flat index m = 12*n + f goes to bucket m/225 (raw-reshape scramble) */
    if (tid < HW) {
        int m0 = 12*tid;
        int a0 = m0/225, a1 = (m0+11)/225;
        if (a0 == a1) {
            float s = 0.f;
#pragma unroll
            for (int f = 0; f < F_CH; ++f) s += accV[f];
            atomicAdd(&vmb[a0], s);
        } else {
            int split = 225*a1 - m0;
            float sa = 0.f, sb = 0.f;
#pragma unroll
            for (int f = 0; f < F_CH; ++f) { if (f < split) sa += accV[f]; else sb += accV[f]; }
            atomicAdd(&vmb[a0], sa);
            atomicAdd(&vmb[a1], sb);
        }
    }
    __syncthreads();

    if (tid == 0) {
        float v[F_CH], mx = -1e30f;
#pragma unroll
        for (int a = 0; a < F_CH; ++a) { v[a] = vmb[a]*(1.f/HW); mx = fmaxf(mx, v[a]); }
        float s = 0.f;
#pragma unroll
        for (int a = 0; a < F_CH; ++a) { v[a] = __expf(v[a]-mx); s += v[a]; }
        float inv = 1.f/s;
#pragma unroll
        for (int a = 0; a < F_CH; ++a) vsS[a] = v[a]*inv;
    }
    __syncthreads();

    if (tid < 6) {
        float s = 0.f;
#pragma unroll
        for (int l = 0; l < F_CH; ++l) s = fmaf(w41[tid*F_CH+l], vsS[l], s);
        t1S[tid] = s;
    }
    __syncthreads();

    float A = 0.f, AD = 0.f;
    if (tid < C_DIM) {
        float s = 0.f;
#pragma unroll
        for (int j = 0; j < 6; ++j) s = fmaf(w42[tid*6+j], t1S[j], s);
        A = s;
        AD = A * Dp[tid];
    }
    float r0 = A, r1 = A*A, r2 = AD;
    for (int o = 32; o > 0; o >>= 1) {
        r0 += __shfl_down(r0, o, 64);
        r1 += __shfl_down(r1, o, 64);
        r2 += __shfl_down(r2, o, 64);
    }
    if ((tid & 63) == 0) { int w = tid>>6; red[w*3]=r0; red[w*3+1]=r1; red[w*3+2]=r2; }
    __syncthreads();
    if (tid == 0) {
        float S0 = red[0]+red[3]+red[6]+red[9];
        float S1 = red[1]+red[4]+red[7]+red[10];
        float S2 = red[2]+red[5]+red[8]+red[11];
        float Am = S0*(1.f/C_DIM);
        AmSh   = Am;
        varASh = S1*(1.f/C_DIM) - Am*Am;
        covSh  = S2*(1.f/C_DIM);
    }
    __syncthreads();

    float* __restrict__ pb = par + (size_t)b*PSTRIDE;
    if (tid < C_DIM) pb[450+tid] = (A - AmSh) * ln_g[tid];
    if (tid < HW) {
        float var = fmaf(kq*kq, varASh, fmaf(2.f*kq, covSh, varD));
        float rs  = rsqrtf(var + LN_EPS);
        pb[tid]      = kq*rs;   /* P[n] */
        pb[HW+tid]   = rs;      /* R[n] */
    }
}

/* ---------- split path: streaming gate multiply, column mode ---------- */
__global__ __launch_bounds__(256) void k_gate(
    const float* __restrict__ X,
    const float* __restrict__ par,
    const float* __restrict__ Dg, const float* __restrict__ ln_b,
    float* __restrict__ out)
{
    const int blk = blockIdx.x;
    const int b   = blk >> 2;          /* CSPL == 4 */
    const int seg = blk & 3;
    const int c0  = seg * CPB;
    const int tid = threadIdx.x;

    __shared__ float AgL[CPB], DgL[CPB], blL[CPB];

    const float* __restrict__ pb = par + (size_t)b*PSTRIDE;
    if (tid < CPB) {
        int c = c0 + tid;
        AgL[tid] = pb[450+c];
        DgL[tid] = Dg[c];
        blL[tid] = ln_b[c];
    }
    float pn = 0.f, rn = 0.f;
    if (tid < HW) { pn = pb[tid]; rn = pb[HW+tid]; }
    __syncthreads();

    if (tid < HW) {
        const float* __restrict__ xb = X   + (size_t)b*PERB + (size_t)c0*HW + tid;
        float*       __restrict__ ob = out + (size_t)b*PERB + (size_t)c0*HW + tid;
        /* 50 rows, unroll x5: 5 loads in flight per wave, conflict-free LDS broadcasts */
        for (int j0 = 0; j0 < CPB; j0 += 5) {
            float xv[5];
#pragma unroll
            for (int u = 0; u < 5; ++u) xv[u] = xb[(size_t)(j0+u)*HW];
#pragma unroll
            for (int u = 0; u < 5; ++u) {
                int j = j0 + u;
                float xn   = fmaf(pn, AgL[j], fmaf(rn, DgL[j], blL[j]));
                float gate = (xn > 0.f) ? (1.f/(1.f+__expf(-xn))) : 0.5f;
                ob[(size_t)j*HW] = gate * xv[u];
            }
        }
    }
}

/* ---------- fallback: original fused kernel (used if ws too small) ---------- */
__global__ __launch_bounds__(256) void k_main(
    const float* __restrict__ X,
    const float* __restrict__ wT,
    const float* __restrict__ b11, const float* __restrict__ b21,
    const float* __restrict__ b31,
    const float* __restrict__ w41,
    const float* __restrict__ w42,
    const float* __restrict__ Dp, const float* __restrict__ varDp,
    const float* __restrict__ ln_g, const float* __restrict__ ln_b,
    float* __restrict__ out)
{
    const int b   = blockIdx.x;
    const int tid = threadIdx.x;

    __shared__ float kqsS[HW];
    __shared__ float vmb[F_CH];
    __shared__ float vsS[F_CH];
    __shared__ float t1S[6];
    __shared__ float red[12];
    __shared__ float AmSh, varASh, covSh;
    __shared__ float AgS[C_DIM], DgS[C_DIM], blS[C_DIM];
    __shared__ float PS[HW], RS[HW];

    const float varD = varDp[0];

    float accK[F_CH], accQ[F_CH], accV[F_CH];
#pragma unroll
    for (int f = 0; f < F_CH; ++f) { accK[f] = b11[f]; accQ[f] = b21[f]; accV[f] = b31[f]; }

    const int n = (tid < HW) ? tid : (HW-1);
    const float* xcol = X + (size_t)b*PERB + n;
    for (int c = 0; c < C_DIM; ++c) {
        float x = xcol[c*HW];
        const float* wr = wT + c*36;
#pragma unroll
        for (int f = 0; f < F_CH; ++f) {
            accK[f] = fmaf(x, wr[f],      accK[f]);
            accQ[f] = fmaf(x, wr[12+f],   accQ[f]);
            accV[f] = fmaf(x, wr[24+f],   accV[f]);
        }
    }

    if (tid < F_CH) vmb[tid] = 0.f;
    if (tid < HW) {
        float s = 0.f;
#pragma unroll
        for (int f = 0; f < F_CH; ++f) s = fmaf(accK[f], accQ[f], s);
        kqsS[tid] = s;
    }
    __syncthreads();

    if (tid < HW) {
        int m0 = 12*tid;
        int a0 = m0/225, a1 = (m0+11)/225;
        if (a0 == a1) {
            float s = 0.f;
#pragma unroll
            for (int f = 0; f < F_CH; ++f) s += accV[f];
            atomicAdd(&vmb[a0], s);
        } else {
            int split = 225*a1 - m0;
            float sa = 0.f, sb = 0.f;
#pragma unroll
            for (int f = 0; f < F_CH; ++f) { if (f < split) sa += accV[f]; else sb += accV[f]; }
            atomicAdd(&vmb[a0], sa);
            atomicAdd(&vmb[a1], sb);
        }
    }
    __syncthreads();

    if (tid == 0) {
        float v[F_CH], mx = -1e30f;
#pragma unroll
        for (int a = 0; a < F_CH; ++a) { v[a] = vmb[a]*(1.f/HW); mx = fmaxf(mx, v[a]); }
        float s = 0.f;
#pragma unroll
        for (int a = 0; a < F_CH; ++a) { v[a] = __expf(v[a]-mx); s += v[a]; }
        float inv = 1.f/s;
#pragma unroll
        for (int a = 0; a < F_CH; ++a) vsS[a] = v[a]*inv;
    }
    __syncthreads();

    if (tid < 6) {
        float s = 0.f;
#pragma unroll
        for (int l = 0; l < F_CH; ++l) s = fmaf(w41[tid*F_CH+l], vsS[l], s);
        t1S[tid] = s;
    }
    __syncthreads();

    float A = 0.f, AD = 0.f;
    if (tid < C_DIM) {
        float s = 0.f;
#pragma unroll
        for (int j = 0; j < 6; ++j) s = fmaf(w42[tid*6+j], t1S[j], s);
        A = s;
        AD = A * Dp[tid];
    }
    float r0 = A, r1 = A*A, r2 = AD;
    for (int o = 32; o > 0; o >>= 1) {
        r0 += __shfl_down(r0, o, 64);
        r1 += __shfl_down(r1, o, 64);
        r2 += __shfl_down(r2, o, 64);
    }
    if ((tid & 63) == 0) { int w = tid>>6; red[w*3]=r0; red[w*3+1]=r1; red[w*3+2]=r2; }
    __syncthreads();
    if (tid == 0) {
        float S0 = red[0]+red[3]+red[6]+red[9];
        float S1 = red[1]+red[4]+red[7]+red[10];
        float S2 = red[2]+red[5]+red[8]+red[11];
        float Am = S0*(1.f/C_DIM);
        AmSh   = Am;
        varASh = S1*(1.f/C_DIM) - Am*Am;
        covSh  = S2*(1.f/C_DIM);
    }
    __syncthreads();

    if (tid < C_DIM) {
        float Ap = A - AmSh;
        float g  = ln_g[tid];
        AgS[tid] = Ap*g;
        DgS[tid] = Dp[tid]*g;
        blS[tid] = ln_b[tid];
    }
    if (tid < HW) {
        float kq  = kqsS[tid];
        float var = fmaf(kq*kq, varASh, fmaf(2.f*kq, covSh, varD));
        float rs  = rsqrtf(var + LN_EPS);
        PS[tid] = kq*rs;
        RS[tid] = rs;
    }
    __syncthreads();

    const float4* __restrict__ X4 = (const float4*)(X + (size_t)b*PERB);
    float4* __restrict__ O4 = (float4*)(out + (size_t)b*PERB);
    for (int i = tid; i < PERB4; i += 256) {
        float4 xv = X4[i];
        float xs[4] = {xv.x, xv.y, xv.z, xv.w};
        float rs4[4];
        unsigned base = (unsigned)i*4u;
#pragma unroll
        for (int e = 0; e < 4; ++e) {
            unsigned idx = base + e;
            unsigned c  = idx / HW;
            unsigned nn = idx - c*HW;
            float xn = fmaf(PS[nn], AgS[c], fmaf(RS[nn], DgS[c], blS[c]));
            float gate = (xn > 0.f) ? (1.f/(1.f+__expf(-xn))) : 0.5f;
            rs4[e] = gate * xs[e];
        }
        float4 ov; ov.x=rs4[0]; ov.y=rs4[1]; ov.z=rs4[2]; ov.w=rs4[3];
        O4[i] = ov;
    }
}

extern "C" void kernel_launch(void* const* d_in, const int* in_sizes, int n_in,
                              void* d_out, int out_size, void* d_ws, size_t ws_size,
                              hipStream_t stream) {
    const float* X   = (const float*)d_in[0];
    const float* w11 = (const float*)d_in[1];
    const float* b11 = (const float*)d_in[2];
    const float* w21 = (const float*)d_in[3];
    const float* b21 = (const float*)d_in[4];
    const float* w31 = (const float*)d_in[5];
    const float* b31 = (const float*)d_in[6];
    const float* w41 = (const float*)d_in[7];
    const float* b41 = (const float*)d_in[8];
    const float* w42 = (const float*)d_in[9];
    const float* b42 = (const float*)d_in[10];
    const float* lng = (const float*)d_in[11];
    const float* lnb = (const float*)d_in[12];
    float* out = (float*)d_out;
    float* ws  = (float*)d_ws;

    float* wT = ws + WS_WT;
    float* Dp = ws + WS_DP;
    float* Dg = ws + WS_DG;
    float* vD = ws + WS_VARD;
    float* par = ws + WS_PAR;

    hipLaunchKernelGGL(k_prep, dim3(1), dim3(256), 0, stream,
                       w11, w21, w31, b41, w42, b42, lng, wT, Dp, Dg, vD);

    if (ws_size >= WS_NEEDED_BYTES) {
        hipLaunchKernelGGL(k_conv, dim3(1024), dim3(256), 0, stream,
                           X, wT, b11, b21, b31, w41, w42, Dp, vD, lng, par);
        hipLaunchKernelGGL(k_gate, dim3(1024*CSPL), dim3(256), 0, stream,
                           X, par, Dg, lnb, out);
    } else {
        hipLaunchKernelGGL(k_main, dim3(1024), dim3(256), 0, stream,
                           X, wT, b11, b21, b31, w41, w42, Dp, vD, lng, lnb, out);
    }
}

// Round 2
// 385.027 us; speedup vs baseline: 1.0384x; 1.0212x over previous
//
#include <hip/hip_runtime.h>
#include <math.h>

#define F_CH 12
#define C_DIM 200
#define HW 225
#define PERB (C_DIM*HW)      /* 45000 */
#define LN_EPS 1e-5f

/* ws layout (floats) */
#define WS_WT   0        /* 7200: wT[c][36] = {w11[:,c], w21[:,c], w31[:,c]} */
#define WS_DP   7200     /* 200:  D'[c] = d[c] - mean(d) */
#define WS_VARD 7400     /* 1:    mean(D'^2) */

__global__ __launch_bounds__(256) void k_prep(
    const float* __restrict__ w11, const float* __restrict__ w21,
    const float* __restrict__ w31, const float* __restrict__ b41,
    const float* __restrict__ w42, const float* __restrict__ b42,
    float* __restrict__ wT, float* __restrict__ Dp, float* __restrict__ varD)
{
    const int tid = threadIdx.x;
    for (int i = tid; i < 36*C_DIM; i += 256) {
        int c = i / 36, g = i - 36*c;
        float v;
        if (g < 12)      v = w11[g*C_DIM + c];
        else if (g < 24) v = w21[(g-12)*C_DIM + c];
        else             v = w31[(g-24)*C_DIM + c];
        wT[i] = v;
    }
    __shared__ float red[12];
    __shared__ float DmSh;
    float d = 0.f;
    if (tid < C_DIM) {
        float s = b42[tid];
#pragma unroll
        for (int j = 0; j < 6; ++j) s = fmaf(w42[tid*6+j], b41[j], s);
        d = s;
    }
    float s0 = d;
    for (int o = 32; o > 0; o >>= 1) s0 += __shfl_down(s0, o, 64);
    if ((tid & 63) == 0) red[tid >> 6] = s0;
    __syncthreads();
    if (tid == 0) DmSh = (red[0]+red[1]+red[2]+red[3]) * (1.f/C_DIM);
    __syncthreads();
    float dp = (tid < C_DIM) ? (d - DmSh) : 0.f;
    if (tid < C_DIM) Dp[tid] = dp;
    float s1 = dp*dp;
    for (int o = 32; o > 0; o >>= 1) s1 += __shfl_down(s1, o, 64);
    if ((tid & 63) == 0) red[4 + (tid >> 6)] = s1;
    __syncthreads();
    if (tid == 0) varD[0] = (red[4]+red[5]+red[6]+red[7]) * (1.f/C_DIM);
}

/* Fused: conv (depth-2 prefetch) + reductions + column-mode gate pass.
   thread = pixel; kq/P/R register-resident; per-c params via LDS broadcast
   (conflict-free); no idx/225 division anywhere. */
__global__ __launch_bounds__(256, 4) void k_fused(
    const float* __restrict__ X,
    const float* __restrict__ wT,
    const float* __restrict__ b11, const float* __restrict__ b21,
    const float* __restrict__ b31,
    const float* __restrict__ w41,
    const float* __restrict__ w42,
    const float* __restrict__ Dp, const float* __restrict__ varDp,
    const float* __restrict__ ln_g, const float* __restrict__ ln_b,
    float* __restrict__ out)
{
    const int b   = blockIdx.x;
    const int tid = threadIdx.x;

    __shared__ float vmb[F_CH];
    __shared__ float vsS[F_CH];
    __shared__ float t1S[6];
    __shared__ float red[12];
    __shared__ float AmSh, varASh, covSh;
    __shared__ float AgS[C_DIM], DgS[C_DIM], blS[C_DIM];

    const float varD = varDp[0];

    float accK[F_CH], accQ[F_CH], accV[F_CH];
#pragma unroll
    for (int f = 0; f < F_CH; ++f) { accK[f] = b11[f]; accQ[f] = b21[f]; accV[f] = b31[f]; }

    /* All 256 threads run the loop (wave-uniform scalar weight loads);
       lanes >= 225 duplicate pixel 224 and are masked from stores/reductions. */
    const int n = (tid < HW) ? tid : (HW-1);
    const float* xcol = X + (size_t)b*PERB + n;

#define CONV_STEP(CBASE, XR)                                              \
    {                                                                     \
        const float* wr_ = wT + (CBASE)*36;                               \
        _Pragma("unroll")                                                 \
        for (int u = 0; u < 4; ++u) {                                     \
            float xv_ = XR[u];                                            \
            const float* wu_ = wr_ + u*36;                                \
            _Pragma("unroll")                                             \
            for (int f = 0; f < F_CH; ++f) {                              \
                accK[f] = fmaf(xv_, wu_[f],    accK[f]);                  \
                accQ[f] = fmaf(xv_, wu_[12+f], accQ[f]);                  \
                accV[f] = fmaf(xv_, wu_[24+f], accV[f]);                  \
            }                                                             \
        }                                                                 \
    }

    /* depth-2 group prefetch: 8 X-loads in flight per wave */
    float xA[4], xB[4];
#pragma unroll
    for (int u = 0; u < 4; ++u) xA[u] = xcol[(size_t)u*HW];
#pragma unroll
    for (int u = 0; u < 4; ++u) xB[u] = xcol[(size_t)(4+u)*HW];
    for (int c = 0; c < C_DIM - 8; c += 4) {
        float xC[4];
        const float* xn4 = xcol + (size_t)(c+8)*HW;
#pragma unroll
        for (int u = 0; u < 4; ++u) xC[u] = xn4[(size_t)u*HW];
        CONV_STEP(c, xA);
#pragma unroll
        for (int u = 0; u < 4; ++u) { xA[u] = xB[u]; xB[u] = xC[u]; }
    }
    CONV_STEP(C_DIM-8, xA);
    CONV_STEP(C_DIM-4, xB);
#undef CONV_STEP

    /* kq stays in a register */
    float kq = 0.f;
#pragma unroll
    for (int f = 0; f < F_CH; ++f) kq = fmaf(accK[f], accQ[f], kq);

    if (tid < F_CH) vmb[tid] = 0.f;
    __syncthreads();

    /* vm bucketing: flat index m = 12*n + f goes to bucket m/225 (raw-reshape scramble) */
    if (tid < HW) {
        int m0 = 12*tid;
        int a0 = m0/225, a1 = (m0+11)/225;
        if (a0 == a1) {
            float s = 0.f;
#pragma unroll
            for (int f = 0; f < F_CH; ++f) s += accV[f];
            atomicAdd(&vmb[a0], s);
        } else {
            int split = 225*a1 - m0;
            float sa = 0.f, sb = 0.f;
#pragma unroll
            for (int f = 0; f < F_CH; ++f) { if (f < split) sa += accV[f]; else sb += accV[f]; }
            atomicAdd(&vmb[a0], sa);
            atomicAdd(&vmb[a1], sb);
        }
    }
    __syncthreads();

    if (tid == 0) {
        float v[F_CH], mx = -1e30f;
#pragma unroll
        for (int a = 0; a < F_CH; ++a) { v[a] = vmb[a]*(1.f/HW); mx = fmaxf(mx, v[a]); }
        float s = 0.f;
#pragma unroll
        for (int a = 0; a < F_CH; ++a) { v[a] = __expf(v[a]-mx); s += v[a]; }
        float inv = 1.f/s;
#pragma unroll
        for (int a = 0; a < F_CH; ++a) vsS[a] = v[a]*inv;
    }
    __syncthreads();

    if (tid < 6) {
        float s = 0.f;
#pragma unroll
        for (int l = 0; l < F_CH; ++l) s = fmaf(w41[tid*F_CH+l], vsS[l], s);
        t1S[tid] = s;
    }
    __syncthreads();

    float A = 0.f, AD = 0.f;
    if (tid < C_DIM) {
        float s = 0.f;
#pragma unroll
        for (int j = 0; j < 6; ++j) s = fmaf(w42[tid*6+j], t1S[j], s);
        A = s;
        AD = A * Dp[tid];
    }
    float r0 = A, r1 = A*A, r2 = AD;
    for (int o = 32; o > 0; o >>= 1) {
        r0 += __shfl_down(r0, o, 64);
        r1 += __shfl_down(r1, o, 64);
        r2 += __shfl_down(r2, o, 64);
    }
    if ((tid & 63) == 0) { int w = tid>>6; red[w*3]=r0; red[w*3+1]=r1; red[w*3+2]=r2; }
    __syncthreads();
    if (tid == 0) {
        float S0 = red[0]+red[3]+red[6]+red[9];
        float S1 = red[1]+red[4]+red[7]+red[10];
        float S2 = red[2]+red[5]+red[8]+red[11];
        float Am = S0*(1.f/C_DIM);
        AmSh   = Am;
        varASh = S1*(1.f/C_DIM) - Am*Am;
        covSh  = S2*(1.f/C_DIM);
    }
    __syncthreads();

    if (tid < C_DIM) {
        float g  = ln_g[tid];
        AgS[tid] = (A - AmSh)*g;
        DgS[tid] = Dp[tid]*g;
        blS[tid] = ln_b[tid];
    }
    float Pn = 0.f, Rn = 0.f;
    if (tid < HW) {
        float var = fmaf(kq*kq, varASh, fmaf(2.f*kq, covSh, varD));
        float rs  = rsqrtf(var + LN_EPS);
        Pn = kq*rs;
        Rn = rs;
    }
    __syncthreads();

    /* phase 2: column-mode gate pass. X re-reads are L2/L3 warm (this block
       just streamed them); params are wave-uniform LDS broadcasts. */
    if (tid < HW) {
        const float* __restrict__ xb = X   + (size_t)b*PERB + tid;
        float*       __restrict__ ob = out + (size_t)b*PERB + tid;
        float v0[4];
#pragma unroll
        for (int u = 0; u < 4; ++u) v0[u] = xb[(size_t)u*HW];
        for (int c = 0; c < C_DIM - 4; c += 4) {
            float nv[4];
            const float* xn4 = xb + (size_t)(c+4)*HW;
#pragma unroll
            for (int u = 0; u < 4; ++u) nv[u] = xn4[(size_t)u*HW];
#pragma unroll
            for (int u = 0; u < 4; ++u) {
                int cc = c + u;
                float xn   = fmaf(Pn, AgS[cc], fmaf(Rn, DgS[cc], blS[cc]));
                float gate = (xn > 0.f) ? (1.f/(1.f+__expf(-xn))) : 0.5f;
                __builtin_nontemporal_store(gate * v0[u], &ob[(size_t)cc*HW]);
            }
#pragma unroll
            for (int u = 0; u < 4; ++u) v0[u] = nv[u];
        }
#pragma unroll
        for (int u = 0; u < 4; ++u) {
            int cc = C_DIM - 4 + u;
            float xn   = fmaf(Pn, AgS[cc], fmaf(Rn, DgS[cc], blS[cc]));
            float gate = (xn > 0.f) ? (1.f/(1.f+__expf(-xn))) : 0.5f;
            __builtin_nontemporal_store(gate * v0[u], &ob[(size_t)cc*HW]);
        }
    }
}

extern "C" void kernel_launch(void* const* d_in, const int* in_sizes, int n_in,
                              void* d_out, int out_size, void* d_ws, size_t ws_size,
                              hipStream_t stream) {
    const float* X   = (const float*)d_in[0];
    const float* w11 = (const float*)d_in[1];
    const float* b11 = (const float*)d_in[2];
    const float* w21 = (const float*)d_in[3];
    const float* b21 = (const float*)d_in[4];
    const float* w31 = (const float*)d_in[5];
    const float* b31 = (const float*)d_in[6];
    const float* w41 = (const float*)d_in[7];
    const float* b41 = (const float*)d_in[8];
    const float* w42 = (const float*)d_in[9];
    const float* b42 = (const float*)d_in[10];
    const float* lng = (const float*)d_in[11];
    const float* lnb = (const float*)d_in[12];
    float* out = (float*)d_out;
    float* ws  = (float*)d_ws;

    float* wT = ws + WS_WT;
    float* Dp = ws + WS_DP;
    float* vD = ws + WS_VARD;

    hipLaunchKernelGGL(k_prep, dim3(1), dim3(256), 0, stream,
                       w11, w21, w31, b41, w42, b42, wT, Dp, vD);
    hipLaunchKernelGGL(k_fused, dim3(1024), dim3(256), 0, stream,
                       X, wT, b11, b21, b31, w41, w42, Dp, vD, lng, lnb, out);
}